// Round 12
// baseline (207.509 us; speedup 1.0000x reference)
//
#include <hip/hip_runtime.h>
#include <math.h>

#define NN 2708
#define IC 1433
#define OC 128
#define NV (NN / 4)          // 677 float4/int4 per row (exact)
#define NNOC ((size_t)NN * OC)
#define NW 85                // ceil(NN/32) bitmap words per row
#define NR 11                // ceil(NN/256) scan rounds per thread

// ============ kernel A: prep2 = { transposeW | wvec | zero u1/sC } (208 blocks) ============
__global__ __launch_bounds__(256) void prep2(const float* __restrict__ W, float* __restrict__ Wt,
                                             const float* __restrict__ a1, const float* __restrict__ a2,
                                             double* __restrict__ w1, double* __restrict__ w2,
                                             double* __restrict__ zd, int nzd) {
  __shared__ float tile[32][33];
  const int b = blockIdx.x, t = threadIdx.x;
  if (b < 180) {
    const int k0 = (b % 45) * 32, o0 = (b / 45) * 32;
#pragma unroll
    for (int it = 0; it < 4; it++) {
      int ro = (t >> 5) + it * 8;
      int k  = k0 + (t & 31);
      tile[ro][t & 31] = (k < IC) ? W[(size_t)(o0 + ro) * IC + k] : 0.f;
    }
    __syncthreads();
#pragma unroll
    for (int it = 0; it < 4; it++) {
      int rk = (t >> 5) + it * 8;
      int k  = k0 + rk;
      if (k < IC) Wt[(size_t)k * OC + o0 + (t & 31)] = tile[t & 31][rk];
    }
  } else if (b < 186) {
    float* a1s = &tile[0][0];
    float* a2s = a1s + 128;
    if (t < 128) { a1s[t] = a1[t]; a2s[t] = a2[t]; }
    __syncthreads();
    int c = (b - 180) * 256 + t;
    if (c < IC) {
      const float* Wc = W + c;
      double s1 = 0.0, s2 = 0.0;
#pragma unroll 4
      for (int o = 0; o < OC; o++) {
        double w = (double)Wc[(size_t)o * IC];
        s1 = fma(w, (double)a1s[o], s1);
        s2 = fma(w, (double)a2s[o], s2);
      }
      w1[c] = s1; w2[c] = s2;
    }
  } else {
    int gid = (b - 186) * 256 + t;
    if (gid < nzd) zd[gid] = 0.0;
  }
}

// ============ kernel B: { gemmK | bitmapA | xw }, INTERLEAVED block->family map ============
// Even blocks <2720 -> gemm (id b/2); odd blocks <2720 -> other (id b/2); b>=2720 -> other (b-1360).
// other id o: o<900 -> bitmapA(o); else xw(o-900). Alternation co-schedules compute (gemm)
// with the cold 29MB A-stream + xw on every CU, hiding memory latency under FMAs.
__global__ __launch_bounds__(256) void xw_gemm(const float* __restrict__ X,
                                               const double* __restrict__ w1, const double* __restrict__ w2,
                                               double* __restrict__ k1, double* __restrict__ k2,
                                               const float* __restrict__ Wt, float* __restrict__ Kp,
                                               const int* __restrict__ A, unsigned* __restrict__ bm,
                                               int chunk, int nsplit) {
  __shared__ __align__(16) char smem[21504];   // gemm: Xs(32x36)+Ws(32x132)
  const int b = blockIdx.x, t = threadIdx.x;
  const int ngm = 85 * nsplit;                  // 1360
  // interleaved family decode
  bool isGemm;
  int fid;                                      // family-local id
  if (b < 2 * ngm) {
    isGemm = ((b & 1) == 0);
    fid = b >> 1;
  } else {
    isGemm = false;
    fid = b - ngm;
  }
  if (isGemm) {
    float (*Xs)[36]  = (float (*)[36])smem;
    float (*Ws)[132] = (float (*)[132])(smem + 32 * 36 * 4);
    const int bx = fid % 85, by = fid / 85;
    const int rb = bx * 32;
    const int ks = by * chunk;
    const int ke = min(IC, ks + chunk);
    float* __restrict__ Ko = Kp + (size_t)by * NNOC;
    const int row0 = (t >> 5) * 4;
    const int col4 = (t & 31) * 4;
    float acc[4][4];
#pragma unroll
    for (int r = 0; r < 4; r++)
#pragma unroll
      for (int c = 0; c < 4; c++) acc[r][c] = 0.f;

    for (int kb = ks; kb < ke; kb += 32) {
#pragma unroll
      for (int it = 0; it < 4; it++) {
        int idx = t + it * 256;
        int r = idx >> 5, c = idx & 31;
        int gr = rb + r, gc = kb + c;
        Xs[r][c] = (gr < NN && gc < ke) ? X[(size_t)gr * IC + gc] : 0.f;
      }
#pragma unroll
      for (int it = 0; it < 4; it++) {
        int idx4 = t + it * 256;
        int k = idx4 >> 5, cg = (idx4 & 31) * 4;
        int gk = kb + k;
        float4 v = make_float4(0.f, 0.f, 0.f, 0.f);
        if (gk < ke) v = *reinterpret_cast<const float4*>(&Wt[(size_t)gk * OC + cg]);
        *reinterpret_cast<float4*>(&Ws[k][cg]) = v;
      }
      __syncthreads();
#pragma unroll
      for (int g = 0; g < 8; g++) {
        float xr[4][4];
#pragma unroll
        for (int r = 0; r < 4; r++)
          *reinterpret_cast<float4*>(xr[r]) = *reinterpret_cast<const float4*>(&Xs[row0 + r][g * 4]);
#pragma unroll
        for (int j = 0; j < 4; j++) {
          const float4 w4 = *reinterpret_cast<const float4*>(&Ws[g * 4 + j][col4]);
#pragma unroll
          for (int r = 0; r < 4; r++) {
            acc[r][0] = fmaf(xr[r][j], w4.x, acc[r][0]);
            acc[r][1] = fmaf(xr[r][j], w4.y, acc[r][1]);
            acc[r][2] = fmaf(xr[r][j], w4.z, acc[r][2]);
            acc[r][3] = fmaf(xr[r][j], w4.w, acc[r][3]);
          }
        }
      }
      __syncthreads();
    }
#pragma unroll
    for (int r = 0; r < 4; r++) {
      int gr = rb + row0 + r;
      if (gr < NN) {
        float4 v = make_float4(acc[r][0], acc[r][1], acc[r][2], acc[r][3]);
        *reinterpret_cast<float4*>(&Ko[(size_t)gr * OC + col4]) = v;
      }
    }
  } else if (fid < 900) {
    int gid = fid * 256 + t;
    const int total = NN * NW;
    if (gid >= total) return;
    int i = gid / NW, w = gid - i * NW;
    const int* Ar = A + (size_t)i * NN + w * 32;
    unsigned word = 0;
    if (w < NW - 1) {
      const int4* a4 = (const int4*)Ar;
#pragma unroll
      for (int u = 0; u < 8; u++) {
        int4 a = a4[u];
        word |= (a.x != 0 ? 1u : 0u) << (4 * u);
        word |= (a.y != 0 ? 1u : 0u) << (4 * u + 1);
        word |= (a.z != 0 ? 1u : 0u) << (4 * u + 2);
        word |= (a.w != 0 ? 1u : 0u) << (4 * u + 3);
      }
    } else {
      const int nbits = NN - w * 32;
      for (int bb2 = 0; bb2 < nbits; bb2++) word |= (Ar[bb2] != 0 ? 1u : 0u) << bb2;
    }
    bm[(size_t)i * NW + w] = word;
  } else {
    const int bb = fid - 900;
    const int wave = t >> 6, lane = t & 63;
    const int i = bb * 4 + wave;
    if (i >= NN) return;
    const float* Xi = X + (size_t)i * IC;
    double s1 = 0.0, s2 = 0.0;
    for (int c = lane; c < IC; c += 64) {
      double x = (double)Xi[c];
      s1 = fma(x, w1[c], s1);
      s2 = fma(x, w2[c], s2);
    }
    for (int o = 32; o; o >>= 1) { s1 += __shfl_down(s1, o, 64); s2 += __shfl_down(s2, o, 64); }
    if (lane == 0) { k1[i] = s1; k2[i] = s2; }
  }
}

// ============ kernel C: { ut_reduce | mergeK }, 256-thread blocks ============
// blocks [0,255): u1 = U^T@k1, s = U^T@1 (fp64, atomics); slab=b/3 (32 rows), chunk=b%3 (256 cols4)
// blocks [255, 255+339): merge split-K partials (deterministic order, deep load ILP)
__global__ __launch_bounds__(256) void mid(const float4* __restrict__ U4, const double* __restrict__ k1,
                                           double* __restrict__ u1, double* __restrict__ s,
                                           const float4* __restrict__ Kp4, float4* __restrict__ Kf4,
                                           int nsplit) {
  const int b = blockIdx.x, t = threadIdx.x;
  if (b < 255) {
    const int slab = b / 3, chunk = b - slab * 3;
    const int c4 = chunk * 256 + t;
    if (c4 >= NV) return;
    const int r0 = slab * 32;
    const int r1 = min(NN, r0 + 32);
    double au0 = 0, au1_ = 0, au2 = 0, au3 = 0, as0 = 0, as1 = 0, as2 = 0, as3 = 0;
#pragma unroll 4
    for (int r = r0; r < r1; r++) {
      float4 u = U4[(size_t)r * NV + c4];
      double kr = k1[r];
      au0 = fma((double)u.x, kr, au0); au1_ = fma((double)u.y, kr, au1_);
      au2 = fma((double)u.z, kr, au2); au3 = fma((double)u.w, kr, au3);
      as0 += (double)u.x; as1 += (double)u.y; as2 += (double)u.z; as3 += (double)u.w;
    }
    int c = c4 * 4;
    atomicAdd(&u1[c + 0], au0); atomicAdd(&u1[c + 1], au1_);
    atomicAdd(&u1[c + 2], au2); atomicAdd(&u1[c + 3], au3);
    atomicAdd(&s[c + 0], as0);  atomicAdd(&s[c + 1], as1);
    atomicAdd(&s[c + 2], as2);  atomicAdd(&s[c + 3], as3);
  } else {
    size_t i = (size_t)(b - 255) * 256 + t;
    const size_t n4 = NNOC / 4;
    if (i >= n4) return;
    float4 sv;
    if (nsplit == 16) {
      float4 v[16];
#pragma unroll
      for (int pp = 0; pp < 16; pp++) v[pp] = Kp4[(size_t)pp * n4 + i];
      sv = v[0];
#pragma unroll
      for (int pp = 1; pp < 16; pp++) {
        sv.x += v[pp].x; sv.y += v[pp].y; sv.z += v[pp].z; sv.w += v[pp].w;
      }
    } else if (nsplit == 8) {
      float4 v[8];
#pragma unroll
      for (int pp = 0; pp < 8; pp++) v[pp] = Kp4[(size_t)pp * n4 + i];
      sv = v[0];
#pragma unroll
      for (int pp = 1; pp < 8; pp++) {
        sv.x += v[pp].x; sv.y += v[pp].y; sv.z += v[pp].z; sv.w += v[pp].w;
      }
    } else {
      sv = Kp4[i];
      for (int pp = 1; pp < nsplit; pp++) {
        float4 v = Kp4[(size_t)pp * n4 + i];
        sv.x += v.x; sv.y += v.y; sv.z += v.z; sv.w += v.w;
      }
    }
    Kf4[i] = sv;
  }
}

// ============ kernel E: inline uv + SINGLE-scan softmax (register-cached av) + deep-ILP gather ============
__global__ __launch_bounds__(256) void softuvH(const unsigned* __restrict__ bm,
                                               const float4* __restrict__ U4, const float4* __restrict__ L4,
                                               const double2* __restrict__ u1d, const double2* __restrict__ sd,
                                               const double* __restrict__ k2,
                                               const float* __restrict__ K, float* __restrict__ H) {
  __shared__ float vf[NN];
  __shared__ short js[NN];
  __shared__ float hpart[4][128];
  __shared__ unsigned bmr[NW];
  __shared__ double redd[4], redp[4], redq[4];
  __shared__ float redf[4];
  __shared__ int cntS;

  const int i = blockIdx.x;
  const int t = threadIdx.x;
  const int wv = t >> 6, lane = t & 63;
  const unsigned long long ltmask = (1ull << lane) - 1ull;

  if (t < NW) bmr[t] = bm[(size_t)i * NW + t];
  if (t == 0) cntS = 0;

  // ---- inline uv: p_i, q_i ----
  const float4* Ur = U4 + (size_t)i * NV;
  double ap = 0.0, aq = 0.0;
  for (int c4 = t; c4 < NV; c4 += 256) {
    float4 u = Ur[c4];
    float4 lm = L4[c4];
    double2 ua = u1d[c4 * 2], ub = u1d[c4 * 2 + 1];
    double2 sa = sd[c4 * 2],  sb = sd[c4 * 2 + 1];
    ap = fma((double)u.x, (double)lm.x * ua.x, ap);
    ap = fma((double)u.y, (double)lm.y * ua.y, ap);
    ap = fma((double)u.z, (double)lm.z * ub.x, ap);
    ap = fma((double)u.w, (double)lm.w * ub.y, ap);
    aq = fma((double)u.x, (double)lm.x * sa.x, aq);
    aq = fma((double)u.y, (double)lm.y * sa.y, aq);
    aq = fma((double)u.z, (double)lm.z * sb.x, aq);
    aq = fma((double)u.w, (double)lm.w * sb.y, aq);
  }
  for (int o = 32; o; o >>= 1) { ap += __shfl_down(ap, o, 64); aq += __shfl_down(aq, o, 64); }
  if (lane == 0) { redp[wv] = ap; redq[wv] = aq; }
  __syncthreads();                          // redp/redq + bmr visible
  const double pi = (redp[0] + redp[1]) + (redp[2] + redp[3]);
  const double qi = (redq[0] + redq[1]) + (redq[2] + redq[3]);

  // ---- single scan: av[r] in registers + exact neighbor max ----
  double av[NR];
  double m = -1e300;
#pragma unroll
  for (int r = 0; r < NR; r++) {
    int j = t + r * 256;
    bool nb = (j < NN) && ((bmr[j >> 5] >> (j & 31)) & 1u);
    double a = nb ? fabs(fma(qi, k2[j], pi)) : -1e300;
    av[r] = a;
    m = fmax(m, a);
  }
  for (int o = 32; o; o >>= 1) m = fmax(m, __shfl_xor(m, o, 64));
  if (lane == 0) redd[wv] = m;
  __syncthreads();
  m = fmax(fmax(redd[0], redd[1]), fmax(redd[2], redd[3]));

  // ---- keep/weight/compact from registers (no memory re-scan) ----
  const double thr = m - 21.0;     // exp(-21) ~ 7.6e-10 relative mass cut
  float sw = 0.f;
#pragma unroll
  for (int r = 0; r < NR; r++) {
    bool keep = (av[r] > thr);     // av = -1e300 for non-neighbors/oob -> false
    unsigned long long mask = __ballot(keep);
    if (mask) {
      int src = __ffsll(mask) - 1;          // first keeper in wave
      int basew = 0;
      if (lane == src) basew = atomicAdd(&cntS, __popcll(mask));
      basew = __shfl(basew, src, 64);
      if (keep) {
        int pos = basew + __popcll(mask & ltmask);
        float w = __expf((float)(av[r] - m));
        js[pos] = (short)(t + r * 256);
        vf[pos] = w;
        sw += w;
      }
    }
  }
  for (int o = 32; o; o >>= 1) sw += __shfl_xor(sw, o, 64);
  if (lane == 0) redf[wv] = sw;
  __syncthreads();                          // vf/js/cntS/redf all visible
  const float sumw = (redf[0] + redf[1]) + (redf[2] + redf[3]);
  const int nlist = cntS;

  // ---- gather: 8 candidates per batch (stride 4 per wave), 16 global loads in flight ----
  const int ch = t & 63, g = t >> 6;
  float a0 = 0.f, a1 = 0.f;
  int c = g;
  for (; c + 28 < nlist; c += 32) {
    float wr[8]; int jr[8];
#pragma unroll
    for (int u = 0; u < 8; u++) { wr[u] = vf[c + 4 * u]; jr[u] = js[c + 4 * u]; }
    float kl[8], kh[8];
#pragma unroll
    for (int u = 0; u < 8; u++) {
      const float* Kr = K + (size_t)jr[u] * OC;
      kl[u] = Kr[ch]; kh[u] = Kr[64 + ch];
    }
#pragma unroll
    for (int u = 0; u < 8; u++) { a0 = fmaf(wr[u], kl[u], a0); a1 = fmaf(wr[u], kh[u], a1); }
  }
  for (; c < nlist; c += 4) {
    float w = vf[c];
    const float* Kr = K + (size_t)js[c] * OC;
    a0 = fmaf(w, Kr[ch], a0);
    a1 = fmaf(w, Kr[64 + ch], a1);
  }
  hpart[g][ch] = a0;
  hpart[g][64 + ch] = a1;
  __syncthreads();
  if (t < 128) {
    float hv = (hpart[0][t] + hpart[1][t]) + (hpart[2][t] + hpart[3][t]);
    H[(size_t)i * OC + t] = hv / sumw;
  }
}

extern "C" void kernel_launch(void* const* d_in, const int* in_sizes, int n_in,
                              void* d_out, int out_size, void* d_ws, size_t ws_size,
                              hipStream_t stream) {
  const float* X    = (const float*)d_in[0];
  const int*   A    = (const int*)d_in[1];
  const float* U    = (const float*)d_in[2];
  const float* W    = (const float*)d_in[3];
  const float* a1   = (const float*)d_in[4];
  const float* a2   = (const float*)d_in[5];
  const float* lmbd = (const float*)d_in[6];
  float* H = (float*)d_out;

  const size_t wt_bytes  = (size_t)IC * OC * 4;
  const size_t bm_bytes  = (size_t)NN * NW * 4;
  const size_t dbl_bytes = (size_t)(6 * NN + 2 * IC) * 8;

  // split-K cascade by workspace size (16 proven best: short gemm poles)
  const int splits[5] = {16, 8, 4, 2, 1};
  int nsplit = 1;
  for (int ci = 0; ci < 5; ci++) {
    int ns = splits[ci];
    size_t need = (size_t)(ns > 1 ? ns + 1 : 1) * NNOC * 4 + wt_bytes + dbl_bytes +
                  bm_bytes + 1024;
    if (need <= ws_size) { nsplit = ns; break; }
  }

  char* base = (char*)d_ws;
  float* Kp = (float*)base;
  float* Kf = (nsplit > 1) ? (float*)(base + (size_t)nsplit * NNOC * 4) : Kp;
  size_t off = (size_t)(nsplit > 1 ? nsplit + 1 : 1) * NNOC * 4;
  float* Wt = (float*)(base + off);            off += wt_bytes;
  double* dbl = (double*)(base + off);         off += dbl_bytes;
  double* k1  = dbl;
  double* k2  = k1 + NN;
  double* u1  = k2 + NN;
  double* sC  = u1 + NN;
  double* w1  = sC + NN + 2 * NN;              // (retired p,q slots kept for layout stability)
  double* w2  = w1 + IC;
  unsigned* bm = (unsigned*)(base + off);      off += bm_bytes;

  const int chunk = (IC + nsplit - 1) / nsplit;
  const int nmerge = (int)((NNOC / 4 + 255) / 256);   // 339

  // A: transposeW | wvec | zero u1/sC        (180 + 6 + 22 = 208 blocks)
  prep2<<<208, 256, 0, stream>>>(W, Wt, a1, a2, w1, w2, u1, 2 * NN);
  // B: gemmK | bitmapA | xw, interleaved      (85*nsplit + 900 + 677 blocks)
  xw_gemm<<<85 * nsplit + 900 + 677, 256, 0, stream>>>(X, w1, w2, k1, k2, Wt, Kp, A, bm,
                                                       chunk, nsplit);
  // C: ut_reduce | mergeK                     (255 + 339 blocks of 256)
  mid<<<255 + (nsplit > 1 ? nmerge : 0), 256, 0, stream>>>((const float4*)U, k1, u1, sC,
                                                           (const float4*)Kp, (float4*)Kf, nsplit);
  // E: inline-uv + single-scan softmax + deep-ILP gather
  softuvH<<<NN, 256, 0, stream>>>(bm, (const float4*)U, (const float4*)lmbd,
                                  (const double2*)u1, (const double2*)sC, k2, Kf, H);
}

// Round 13
// 199.867 us; speedup vs baseline: 1.0382x; 1.0382x over previous
//
#include <hip/hip_runtime.h>
#include <math.h>

#define NN 2708
#define IC 1433
#define OC 128
#define NV (NN / 4)          // 677 float4/int4 per row (exact)
#define NNOC ((size_t)NN * OC)
#define NW 85                // ceil(NN/32) bitmap words per row
#define NR 11                // ceil(NN/256) scan rounds per thread

// ============ kernel A: prep2 = { transposeW | wvec | zero u1/sC } (208 blocks) ============
__global__ __launch_bounds__(256) void prep2(const float* __restrict__ W, float* __restrict__ Wt,
                                             const float* __restrict__ a1, const float* __restrict__ a2,
                                             double* __restrict__ w1, double* __restrict__ w2,
                                             double* __restrict__ zd, int nzd) {
  __shared__ float tile[32][33];
  const int b = blockIdx.x, t = threadIdx.x;
  if (b < 180) {
    const int k0 = (b % 45) * 32, o0 = (b / 45) * 32;
#pragma unroll
    for (int it = 0; it < 4; it++) {
      int ro = (t >> 5) + it * 8;
      int k  = k0 + (t & 31);
      tile[ro][t & 31] = (k < IC) ? W[(size_t)(o0 + ro) * IC + k] : 0.f;
    }
    __syncthreads();
#pragma unroll
    for (int it = 0; it < 4; it++) {
      int rk = (t >> 5) + it * 8;
      int k  = k0 + rk;
      if (k < IC) Wt[(size_t)k * OC + o0 + (t & 31)] = tile[t & 31][rk];
    }
  } else if (b < 186) {
    float* a1s = &tile[0][0];
    float* a2s = a1s + 128;
    if (t < 128) { a1s[t] = a1[t]; a2s[t] = a2[t]; }
    __syncthreads();
    int c = (b - 180) * 256 + t;
    if (c < IC) {
      const float* Wc = W + c;
      double s1 = 0.0, s2 = 0.0;
#pragma unroll 4
      for (int o = 0; o < OC; o++) {
        double w = (double)Wc[(size_t)o * IC];
        s1 = fma(w, (double)a1s[o], s1);
        s2 = fma(w, (double)a2s[o], s2);
      }
      w1[c] = s1; w2[c] = s2;
    }
  } else {
    int gid = (b - 186) * 256 + t;
    if (gid < nzd) zd[gid] = 0.0;
  }
}

// ============ kernel B: { gemmK | bitmapA | xw } (grouped family layout — proven best) ============
// blocks [0, 85*nsplit): K partials = X @ Wt over k-chunk (fp32) — long poles first
// blocks [+900): bitmap of A (independent streaming)
// blocks [+677): k1 = X@w1, k2 = X@w2 (fp64, direct L2-broadcast w reads), one wave per row
__global__ __launch_bounds__(256) void xw_gemm(const float* __restrict__ X,
                                               const double* __restrict__ w1, const double* __restrict__ w2,
                                               double* __restrict__ k1, double* __restrict__ k2,
                                               const float* __restrict__ Wt, float* __restrict__ Kp,
                                               const int* __restrict__ A, unsigned* __restrict__ bm,
                                               int chunk, int nsplit) {
  __shared__ __align__(16) char smem[21504];   // gemm: Xs(32x36)+Ws(32x132)
  const int b = blockIdx.x, t = threadIdx.x;
  const int ngm = 85 * nsplit;
  if (b < ngm) {
    float (*Xs)[36]  = (float (*)[36])smem;
    float (*Ws)[132] = (float (*)[132])(smem + 32 * 36 * 4);
    const int bx = b % 85, by = b / 85;
    const int rb = bx * 32;
    const int ks = by * chunk;
    const int ke = min(IC, ks + chunk);
    float* __restrict__ Ko = Kp + (size_t)by * NNOC;
    const int row0 = (t >> 5) * 4;
    const int col4 = (t & 31) * 4;
    float acc[4][4];
#pragma unroll
    for (int r = 0; r < 4; r++)
#pragma unroll
      for (int c = 0; c < 4; c++) acc[r][c] = 0.f;

    for (int kb = ks; kb < ke; kb += 32) {
#pragma unroll
      for (int it = 0; it < 4; it++) {
        int idx = t + it * 256;
        int r = idx >> 5, c = idx & 31;
        int gr = rb + r, gc = kb + c;
        Xs[r][c] = (gr < NN && gc < ke) ? X[(size_t)gr * IC + gc] : 0.f;
      }
#pragma unroll
      for (int it = 0; it < 4; it++) {
        int idx4 = t + it * 256;
        int k = idx4 >> 5, cg = (idx4 & 31) * 4;
        int gk = kb + k;
        float4 v = make_float4(0.f, 0.f, 0.f, 0.f);
        if (gk < ke) v = *reinterpret_cast<const float4*>(&Wt[(size_t)gk * OC + cg]);
        *reinterpret_cast<float4*>(&Ws[k][cg]) = v;
      }
      __syncthreads();
#pragma unroll
      for (int g = 0; g < 8; g++) {
        float xr[4][4];
#pragma unroll
        for (int r = 0; r < 4; r++)
          *reinterpret_cast<float4*>(xr[r]) = *reinterpret_cast<const float4*>(&Xs[row0 + r][g * 4]);
#pragma unroll
        for (int j = 0; j < 4; j++) {
          const float4 w4 = *reinterpret_cast<const float4*>(&Ws[g * 4 + j][col4]);
#pragma unroll
          for (int r = 0; r < 4; r++) {
            acc[r][0] = fmaf(xr[r][j], w4.x, acc[r][0]);
            acc[r][1] = fmaf(xr[r][j], w4.y, acc[r][1]);
            acc[r][2] = fmaf(xr[r][j], w4.z, acc[r][2]);
            acc[r][3] = fmaf(xr[r][j], w4.w, acc[r][3]);
          }
        }
      }
      __syncthreads();
    }
#pragma unroll
    for (int r = 0; r < 4; r++) {
      int gr = rb + row0 + r;
      if (gr < NN) {
        float4 v = make_float4(acc[r][0], acc[r][1], acc[r][2], acc[r][3]);
        *reinterpret_cast<float4*>(&Ko[(size_t)gr * OC + col4]) = v;
      }
    }
  } else if (b < ngm + 900) {
    const int bb = b - ngm;
    int gid = bb * 256 + t;
    const int total = NN * NW;
    if (gid >= total) return;
    int i = gid / NW, w = gid - i * NW;
    const int* Ar = A + (size_t)i * NN + w * 32;
    unsigned word = 0;
    if (w < NW - 1) {
      const int4* a4 = (const int4*)Ar;
#pragma unroll
      for (int u = 0; u < 8; u++) {
        int4 a = a4[u];
        word |= (a.x != 0 ? 1u : 0u) << (4 * u);
        word |= (a.y != 0 ? 1u : 0u) << (4 * u + 1);
        word |= (a.z != 0 ? 1u : 0u) << (4 * u + 2);
        word |= (a.w != 0 ? 1u : 0u) << (4 * u + 3);
      }
    } else {
      const int nbits = NN - w * 32;
      for (int bb2 = 0; bb2 < nbits; bb2++) word |= (Ar[bb2] != 0 ? 1u : 0u) << bb2;
    }
    bm[(size_t)i * NW + w] = word;
  } else {
    const int bb = b - ngm - 900;
    const int wave = t >> 6, lane = t & 63;
    const int i = bb * 4 + wave;
    if (i >= NN) return;
    const float* Xi = X + (size_t)i * IC;
    double s1 = 0.0, s2 = 0.0;
    for (int c = lane; c < IC; c += 64) {
      double x = (double)Xi[c];
      s1 = fma(x, w1[c], s1);
      s2 = fma(x, w2[c], s2);
    }
    for (int o = 32; o; o >>= 1) { s1 += __shfl_down(s1, o, 64); s2 += __shfl_down(s2, o, 64); }
    if (lane == 0) { k1[i] = s1; k2[i] = s2; }
  }
}

// ============ kernel C: { ut_reduce | mergeK }, 256-thread blocks ============
// blocks [0,255): u1 = U^T@k1, s = U^T@1 (fp64, atomics); slab=b/3 (32 rows), chunk=b%3 (256 cols4)
// blocks [255, 255+339): merge split-K partials (deterministic order, deep load ILP)
__global__ __launch_bounds__(256) void mid(const float4* __restrict__ U4, const double* __restrict__ k1,
                                           double* __restrict__ u1, double* __restrict__ s,
                                           const float4* __restrict__ Kp4, float4* __restrict__ Kf4,
                                           int nsplit) {
  const int b = blockIdx.x, t = threadIdx.x;
  if (b < 255) {
    const int slab = b / 3, chunk = b - slab * 3;
    const int c4 = chunk * 256 + t;
    if (c4 >= NV) return;
    const int r0 = slab * 32;
    const int r1 = min(NN, r0 + 32);
    double au0 = 0, au1_ = 0, au2 = 0, au3 = 0, as0 = 0, as1 = 0, as2 = 0, as3 = 0;
#pragma unroll 4
    for (int r = r0; r < r1; r++) {
      float4 u = U4[(size_t)r * NV + c4];
      double kr = k1[r];
      au0 = fma((double)u.x, kr, au0); au1_ = fma((double)u.y, kr, au1_);
      au2 = fma((double)u.z, kr, au2); au3 = fma((double)u.w, kr, au3);
      as0 += (double)u.x; as1 += (double)u.y; as2 += (double)u.z; as3 += (double)u.w;
    }
    int c = c4 * 4;
    atomicAdd(&u1[c + 0], au0); atomicAdd(&u1[c + 1], au1_);
    atomicAdd(&u1[c + 2], au2); atomicAdd(&u1[c + 3], au3);
    atomicAdd(&s[c + 0], as0);  atomicAdd(&s[c + 1], as1);
    atomicAdd(&s[c + 2], as2);  atomicAdd(&s[c + 3], as3);
  } else {
    size_t i = (size_t)(b - 255) * 256 + t;
    const size_t n4 = NNOC / 4;
    if (i >= n4) return;
    float4 sv;
    if (nsplit == 16) {
      float4 v[16];
#pragma unroll
      for (int pp = 0; pp < 16; pp++) v[pp] = Kp4[(size_t)pp * n4 + i];
      sv = v[0];
#pragma unroll
      for (int pp = 1; pp < 16; pp++) {
        sv.x += v[pp].x; sv.y += v[pp].y; sv.z += v[pp].z; sv.w += v[pp].w;
      }
    } else if (nsplit == 8) {
      float4 v[8];
#pragma unroll
      for (int pp = 0; pp < 8; pp++) v[pp] = Kp4[(size_t)pp * n4 + i];
      sv = v[0];
#pragma unroll
      for (int pp = 1; pp < 8; pp++) {
        sv.x += v[pp].x; sv.y += v[pp].y; sv.z += v[pp].z; sv.w += v[pp].w;
      }
    } else {
      sv = Kp4[i];
      for (int pp = 1; pp < nsplit; pp++) {
        float4 v = Kp4[(size_t)pp * n4 + i];
        sv.x += v.x; sv.y += v.y; sv.z += v.z; sv.w += v.w;
      }
    }
    Kf4[i] = sv;
  }
}

// ============ kernel E: inline uv + SINGLE-scan softmax (register-cached av) + deep-ILP gather ============
__global__ __launch_bounds__(256) void softuvH(const unsigned* __restrict__ bm,
                                               const float4* __restrict__ U4, const float4* __restrict__ L4,
                                               const double2* __restrict__ u1d, const double2* __restrict__ sd,
                                               const double* __restrict__ k2,
                                               const float* __restrict__ K, float* __restrict__ H) {
  __shared__ float vf[NN];
  __shared__ short js[NN];
  __shared__ float hpart[4][128];
  __shared__ unsigned bmr[NW];
  __shared__ double redd[4], redp[4], redq[4];
  __shared__ float redf[4];
  __shared__ int cntS;

  const int i = blockIdx.x;
  const int t = threadIdx.x;
  const int wv = t >> 6, lane = t & 63;
  const unsigned long long ltmask = (1ull << lane) - 1ull;

  if (t < NW) bmr[t] = bm[(size_t)i * NW + t];
  if (t == 0) cntS = 0;

  // ---- inline uv: p_i, q_i ----
  const float4* Ur = U4 + (size_t)i * NV;
  double ap = 0.0, aq = 0.0;
  for (int c4 = t; c4 < NV; c4 += 256) {
    float4 u = Ur[c4];
    float4 lm = L4[c4];
    double2 ua = u1d[c4 * 2], ub = u1d[c4 * 2 + 1];
    double2 sa = sd[c4 * 2],  sb = sd[c4 * 2 + 1];
    ap = fma((double)u.x, (double)lm.x * ua.x, ap);
    ap = fma((double)u.y, (double)lm.y * ua.y, ap);
    ap = fma((double)u.z, (double)lm.z * ub.x, ap);
    ap = fma((double)u.w, (double)lm.w * ub.y, ap);
    aq = fma((double)u.x, (double)lm.x * sa.x, aq);
    aq = fma((double)u.y, (double)lm.y * sa.y, aq);
    aq = fma((double)u.z, (double)lm.z * sb.x, aq);
    aq = fma((double)u.w, (double)lm.w * sb.y, aq);
  }
  for (int o = 32; o; o >>= 1) { ap += __shfl_down(ap, o, 64); aq += __shfl_down(aq, o, 64); }
  if (lane == 0) { redp[wv] = ap; redq[wv] = aq; }
  __syncthreads();                          // redp/redq + bmr visible
  const double pi = (redp[0] + redp[1]) + (redp[2] + redp[3]);
  const double qi = (redq[0] + redq[1]) + (redq[2] + redq[3]);

  // ---- single scan: av[r] in registers + exact neighbor max ----
  double av[NR];
  double m = -1e300;
#pragma unroll
  for (int r = 0; r < NR; r++) {
    int j = t + r * 256;
    bool nb = (j < NN) && ((bmr[j >> 5] >> (j & 31)) & 1u);
    double a = nb ? fabs(fma(qi, k2[j], pi)) : -1e300;
    av[r] = a;
    m = fmax(m, a);
  }
  for (int o = 32; o; o >>= 1) m = fmax(m, __shfl_xor(m, o, 64));
  if (lane == 0) redd[wv] = m;
  __syncthreads();
  m = fmax(fmax(redd[0], redd[1]), fmax(redd[2], redd[3]));

  // ---- keep/weight/compact from registers (no memory re-scan) ----
  const double thr = m - 21.0;     // exp(-21) ~ 7.6e-10 relative mass cut
  float sw = 0.f;
#pragma unroll
  for (int r = 0; r < NR; r++) {
    bool keep = (av[r] > thr);     // av = -1e300 for non-neighbors/oob -> false
    unsigned long long mask = __ballot(keep);
    if (mask) {
      int src = __ffsll(mask) - 1;          // first keeper in wave
      int basew = 0;
      if (lane == src) basew = atomicAdd(&cntS, __popcll(mask));
      basew = __shfl(basew, src, 64);
      if (keep) {
        int pos = basew + __popcll(mask & ltmask);
        float w = __expf((float)(av[r] - m));
        js[pos] = (short)(t + r * 256);
        vf[pos] = w;
        sw += w;
      }
    }
  }
  for (int o = 32; o; o >>= 1) sw += __shfl_xor(sw, o, 64);
  if (lane == 0) redf[wv] = sw;
  __syncthreads();                          // vf/js/cntS/redf all visible
  const float sumw = (redf[0] + redf[1]) + (redf[2] + redf[3]);
  const int nlist = cntS;

  // ---- gather: 8 candidates per batch (stride 4 per wave), 16 global loads in flight ----
  const int ch = t & 63, g = t >> 6;
  float a0 = 0.f, a1 = 0.f;
  int c = g;
  for (; c + 28 < nlist; c += 32) {
    float wr[8]; int jr[8];
#pragma unroll
    for (int u = 0; u < 8; u++) { wr[u] = vf[c + 4 * u]; jr[u] = js[c + 4 * u]; }
    float kl[8], kh[8];
#pragma unroll
    for (int u = 0; u < 8; u++) {
      const float* Kr = K + (size_t)jr[u] * OC;
      kl[u] = Kr[ch]; kh[u] = Kr[64 + ch];
    }
#pragma unroll
    for (int u = 0; u < 8; u++) { a0 = fmaf(wr[u], kl[u], a0); a1 = fmaf(wr[u], kh[u], a1); }
  }
  for (; c < nlist; c += 4) {
    float w = vf[c];
    const float* Kr = K + (size_t)js[c] * OC;
    a0 = fmaf(w, Kr[ch], a0);
    a1 = fmaf(w, Kr[64 + ch], a1);
  }
  hpart[g][ch] = a0;
  hpart[g][64 + ch] = a1;
  __syncthreads();
  if (t < 128) {
    float hv = (hpart[0][t] + hpart[1][t]) + (hpart[2][t] + hpart[3][t]);
    H[(size_t)i * OC + t] = hv / sumw;
  }
}

extern "C" void kernel_launch(void* const* d_in, const int* in_sizes, int n_in,
                              void* d_out, int out_size, void* d_ws, size_t ws_size,
                              hipStream_t stream) {
  const float* X    = (const float*)d_in[0];
  const int*   A    = (const int*)d_in[1];
  const float* U    = (const float*)d_in[2];
  const float* W    = (const float*)d_in[3];
  const float* a1   = (const float*)d_in[4];
  const float* a2   = (const float*)d_in[5];
  const float* lmbd = (const float*)d_in[6];
  float* H = (float*)d_out;

  const size_t wt_bytes  = (size_t)IC * OC * 4;
  const size_t bm_bytes  = (size_t)NN * NW * 4;
  const size_t dbl_bytes = (size_t)(6 * NN + 2 * IC) * 8;

  // split-K cascade by workspace size (16 proven best: short gemm poles)
  const int splits[5] = {16, 8, 4, 2, 1};
  int nsplit = 1;
  for (int ci = 0; ci < 5; ci++) {
    int ns = splits[ci];
    size_t need = (size_t)(ns > 1 ? ns + 1 : 1) * NNOC * 4 + wt_bytes + dbl_bytes +
                  bm_bytes + 1024;
    if (need <= ws_size) { nsplit = ns; break; }
  }

  char* base = (char*)d_ws;
  float* Kp = (float*)base;
  float* Kf = (nsplit > 1) ? (float*)(base + (size_t)nsplit * NNOC * 4) : Kp;
  size_t off = (size_t)(nsplit > 1 ? nsplit + 1 : 1) * NNOC * 4;
  float* Wt = (float*)(base + off);            off += wt_bytes;
  double* dbl = (double*)(base + off);         off += dbl_bytes;
  double* k1  = dbl;
  double* k2  = k1 + NN;
  double* u1  = k2 + NN;
  double* sC  = u1 + NN;
  double* w1  = sC + NN + 2 * NN;              // (retired p,q slots kept for layout stability)
  double* w2  = w1 + IC;
  unsigned* bm = (unsigned*)(base + off);      off += bm_bytes;

  const int chunk = (IC + nsplit - 1) / nsplit;
  const int nmerge = (int)((NNOC / 4 + 255) / 256);   // 339

  // A: transposeW | wvec | zero u1/sC        (180 + 6 + 22 = 208 blocks)
  prep2<<<208, 256, 0, stream>>>(W, Wt, a1, a2, w1, w2, u1, 2 * NN);
  // B: gemmK | bitmapA | xw (grouped)         (85*nsplit + 900 + 677 blocks)
  xw_gemm<<<85 * nsplit + 900 + 677, 256, 0, stream>>>(X, w1, w2, k1, k2, Wt, Kp, A, bm,
                                                       chunk, nsplit);
  // C: ut_reduce | mergeK                     (255 + 339 blocks of 256)
  mid<<<255 + (nsplit > 1 ? nmerge : 0), 256, 0, stream>>>((const float4*)U, k1, u1, sC,
                                                           (const float4*)Kp, (float4*)Kf, nsplit);
  // E: inline-uv + single-scan softmax + deep-ILP gather
  softuvH<<<NN, 256, 0, stream>>>(bm, (const float4*)U, (const float4*)lmbd,
                                  (const double2*)u1, (const double2*)sC, k2, Kf, H);
}